// Round 4
// baseline (498.213 us; speedup 1.0000x reference)
//
#include <hip/hip_runtime.h>
#include <cstdint>

#define S_LEN 2048
#define EMB   2048
#define NHEAD 32
#define NKV   8
#define HDIM  64
#define NQKV  3072   // (H+2G)*D
#define KPAD  68

typedef __attribute__((ext_vector_type(8))) short bf16x8;
typedef __attribute__((ext_vector_type(4))) float f32x4;

__device__ __forceinline__ unsigned short f2bf(float f){
  union { float f; unsigned int u; } v; v.f = f;
  unsigned int r = v.u + 0x7FFFu + ((v.u >> 16) & 1u);
  return (unsigned short)(r >> 16);
}
__device__ __forceinline__ float bf2f(unsigned short u){
  union { unsigned int u; float f; } v; v.u = ((unsigned int)u) << 16;
  return v.f;
}

// ---------------- fp32 -> bf16 conversion (vectorized) ----------------
__global__ void cvt_bf16_kernel(const float* __restrict__ in,
                                unsigned short* __restrict__ out, int n4){
  int i = blockIdx.x * 256 + threadIdx.x;
  if (i < n4){
    const float4 v = ((const float4*)in)[i];
    ushort4 o;
    o.x = f2bf(v.x); o.y = f2bf(v.y); o.z = f2bf(v.z); o.w = f2bf(v.w);
    ((ushort4*)out)[i] = o;
  }
}

// ---------------- bf16 MFMA GEMM, C = A * B^T + bias (m97 structure) ----------------
// A: M x K row-major bf16; B: N x K row-major bf16; bias: fp32[N].
// OUT_BF16=1 -> bf16 C; OUT_BF16=0 -> fp32 C (final output buffer is float*).
template<int OUT_BF16>
__global__ __launch_bounds__(256) void gemm_bt(const unsigned short* __restrict__ A,
                                               const unsigned short* __restrict__ B,
                                               const float* __restrict__ bias,
                                               void* __restrict__ Cout,
                                               int M, int N, int K){
  __shared__ unsigned short As[128*32];   // 8 KB
  __shared__ unsigned short Bs[128*32];   // 8 KB
  const int tid  = threadIdx.x;
  const int lane = tid & 63;
  const int wid  = tid >> 6;
  const int m0 = blockIdx.y * 128;
  const int n0 = blockIdx.x * 128;
  const int wm = (wid >> 1) * 64;
  const int wn = (wid & 1) * 64;
  const int fm = lane & 15;
  const int q8 = (lane >> 4) * 8;

  f32x4 acc[4][4];
#pragma unroll
  for (int i = 0; i < 4; ++i)
#pragma unroll
    for (int j = 0; j < 4; ++j) acc[i][j] = {0.f, 0.f, 0.f, 0.f};

  // staging: per wave 32 rows of A-tile and B-tile; 2x 16-row chunks, 16B/lane.
  // HW deposits lane l's 16B at lds_base + l*16 -> row l>>2, cols (l&3)*8.
  const int srow = lane >> 2;          // 0..15
  const int scol = (lane & 3) * 8;     // 0,8,16,24
  const unsigned short* Ag = A + (size_t)(m0 + wid*32 + srow) * K + scol;
  const unsigned short* Bg = B + (size_t)(n0 + wid*32 + srow) * K + scol;
  unsigned short* AsW = &As[(wid*32)*32];   // wave-uniform LDS base
  unsigned short* BsW = &Bs[(wid*32)*32];

  for (int k0 = 0; k0 < K; k0 += 32){
    __syncthreads();
    __builtin_amdgcn_global_load_lds((const __attribute__((address_space(1))) void*)(Ag + k0),
        (__attribute__((address_space(3))) void*)AsW, 16, 0, 0);
    __builtin_amdgcn_global_load_lds((const __attribute__((address_space(1))) void*)(Ag + k0 + (size_t)16*K),
        (__attribute__((address_space(3))) void*)(AsW + 16*32), 16, 0, 0);
    __builtin_amdgcn_global_load_lds((const __attribute__((address_space(1))) void*)(Bg + k0),
        (__attribute__((address_space(3))) void*)BsW, 16, 0, 0);
    __builtin_amdgcn_global_load_lds((const __attribute__((address_space(1))) void*)(Bg + k0 + (size_t)16*K),
        (__attribute__((address_space(3))) void*)(BsW + 16*32), 16, 0, 0);
    __syncthreads();

    bf16x8 af[4], bfr[4];
#pragma unroll
    for (int i = 0; i < 4; ++i) af[i]  = *(const bf16x8*)&As[(wm + i*16 + fm)*32 + q8];
#pragma unroll
    for (int j = 0; j < 4; ++j) bfr[j] = *(const bf16x8*)&Bs[(wn + j*16 + fm)*32 + q8];
#pragma unroll
    for (int i = 0; i < 4; ++i)
#pragma unroll
      for (int j = 0; j < 4; ++j)
        acc[i][j] = __builtin_amdgcn_mfma_f32_16x16x32_bf16(af[i], bfr[j], acc[i][j], 0, 0, 0);
  }

  // epilogue: C/D layout col=lane&15, row=(lane>>4)*4+reg  [measured m89/m91]
  const int quad = lane >> 4;
#pragma unroll
  for (int j = 0; j < 4; ++j){
    const int col = n0 + wn + j*16 + fm;
    const float bv = bias[col];
#pragma unroll
    for (int i = 0; i < 4; ++i){
#pragma unroll
      for (int r = 0; r < 4; ++r){
        const int row = m0 + wm + i*16 + quad*4 + r;
        const float v = acc[i][j][r] + bv;
        if (OUT_BF16) ((unsigned short*)Cout)[(size_t)row*N + col] = f2bf(v);
        else          ((float*)Cout)[(size_t)row*N + col] = v;
      }
    }
  }
}

// ---------------- YaRN RoPE in-place on bf16 qkv (Q heads 0..31, K heads 32..39) ----------------
__global__ void rope_kernel(unsigned short* __restrict__ qkv, const int* __restrict__ pos){
  const int s = blockIdx.x;
  const int head = blockIdx.y;   // 0..39
  const int d = threadIdx.x;     // 0..63
  const int i = d & 31;
  const float freq = __expf(-(float)i * (9.210340371976184f / 32.0f));  // 10000^(-2i/64)
  const float wl = 6.283185307179586f / freq;
  float t = (wl - 128.0f) * (1.0f / 3968.0f);   // low=4096/32, high=4096/1
  t = fminf(fmaxf(t, 0.f), 1.f);
  const float eff = freq * (1.0f - 0.5f * t);   // freq*(1-t) + (freq/2)*t
  const float ang = (float)pos[s] * eff * 1.0693147180559945f;  // conc=0.1*ln(2)+1
  const float c = cosf(ang), sn = sinf(ang);
  const int ch = (head < NHEAD) ? head*HDIM + d : EMB + (head - NHEAD)*HDIM + d;
  unsigned short* p = qkv + (size_t)s * NQKV;
  const float x  = bf2f(p[ch]);
  const float ot = (d < 32) ? bf2f(p[ch + 32]) : bf2f(p[ch - 32]);
  __syncthreads();   // single wave: drains loads before any lane's store
  p[ch] = f2bf((d < 32) ? (x * c - ot * sn) : (x * c + ot * sn));
}

// ---------------- sliding-window GQA attention with sink, online softmax ----------------
// grid (S/64, H), block 256 (4 waves x 16 queries). Keys chunked by 64 over [q0-128, q0+63].
__global__ __launch_bounds__(256) void attn_kernel(const unsigned short* __restrict__ qkv,
                                                   const float* __restrict__ sinks,
                                                   unsigned short* __restrict__ ctxb){
  const int h  = blockIdx.y;
  const int q0 = blockIdx.x * 64;
  const int g  = h >> 2;            // GS = 4
  const int tid  = threadIdx.x;
  const int lane = tid & 63;
  const int wid  = tid >> 6;

  __shared__ float Qc[64*64];            // 16 KB (scaled by 1/sqrt(D))
  __shared__ float Kc[64*KPAD];          // 17 KB (padded for float4 row reads)
  __shared__ float Vc[64*64];            // 16 KB
  __shared__ float Pl[4][16*64];         // 16 KB, per-wave P tile

  for (int idx = tid; idx < 64*64; idx += 256){
    const int r = idx >> 6, d = idx & 63;
    Qc[idx] = bf2f(qkv[(size_t)(q0 + r)*NQKV + h*HDIM + d]) * 0.125f;
  }

  float m_i[16], l_i[16], accq[16];
#pragma unroll
  for (int qi = 0; qi < 16; ++qi){ m_i[qi] = -60000.f; l_i[qi] = 0.f; accq[qi] = 0.f; }

  const int qbase = q0 + wid*16;
  int cs0 = q0 - 128; if (cs0 < 0) cs0 = 0;

  for (int cs = cs0; cs <= q0; cs += 64){
    __syncthreads();
    for (int idx = tid; idx < 64*64; idx += 256){
      const int r = idx >> 6, d = idx & 63;
      const unsigned short* src = qkv + (size_t)(cs + r)*NQKV + EMB + g*HDIM + d;
      Kc[r*KPAD + d] = bf2f(src[0]);
      Vc[r*64  + d]  = bf2f(src[NKV*HDIM]);   // V block starts 512 channels after K
    }
    __syncthreads();

    float4 kr[16];
#pragma unroll
    for (int d4 = 0; d4 < 16; ++d4) kr[d4] = *(const float4*)&Kc[lane*KPAD + d4*4];

    const int key = cs + lane;
#pragma unroll
    for (int qi = 0; qi < 16; ++qi){
      const int qg = qbase + qi;
      const bool valid = (key <= qg) && (key > qg - 128);  // causal + sliding window
      float sc = 0.f;
      const float4* qrow = (const float4*)&Qc[(wid*16 + qi)*64];
#pragma unroll
      for (int d4 = 0; d4 < 16; ++d4){
        const float4 qv = qrow[d4];
        sc += qv.x*kr[d4].x + qv.y*kr[d4].y + qv.z*kr[d4].z + qv.w*kr[d4].w;
      }
      sc = valid ? sc : -60000.f;
      float mx = sc;
#pragma unroll
      for (int off = 32; off; off >>= 1) mx = fmaxf(mx, __shfl_xor(mx, off, 64));
      const float nm = fmaxf(m_i[qi], mx);
      const float p  = valid ? __expf(sc - nm) : 0.f;
      float ps = p;
#pragma unroll
      for (int off = 32; off; off >>= 1) ps += __shfl_xor(ps, off, 64);
      const float alpha = __expf(m_i[qi] - nm);
      m_i[qi] = nm;
      l_i[qi] = l_i[qi]*alpha + ps;
      accq[qi] *= alpha;
      Pl[wid][qi*64 + lane] = p;
    }
    __syncthreads();   // make P tile visible

    // PV: lane = output dim d; batch all 16 queries per V element
#pragma unroll
    for (int j4 = 0; j4 < 16; ++j4){
      const float v0 = Vc[(j4*4+0)*64 + lane];
      const float v1 = Vc[(j4*4+1)*64 + lane];
      const float v2 = Vc[(j4*4+2)*64 + lane];
      const float v3 = Vc[(j4*4+3)*64 + lane];
#pragma unroll
      for (int qi = 0; qi < 16; ++qi){
        const float4 pv = *(const float4*)&Pl[wid][qi*64 + j4*4];
        accq[qi] += pv.x*v0 + pv.y*v1 + pv.z*v2 + pv.w*v3;
      }
    }
  }

  // finalize with sink: softmax over [sink, scores], sink column dropped
  const float snk = sinks[h];
#pragma unroll
  for (int qi = 0; qi < 16; ++qi){
    const float nm = fmaxf(m_i[qi], snk);
    const float e  = __expf(m_i[qi] - nm);
    const float denom = l_i[qi]*e + __expf(snk - nm);
    const float o = accq[qi] * (e / denom);
    ctxb[(size_t)(qbase + qi)*EMB + h*HDIM + lane] = f2bf(o);
  }
}

// ---------------- launch ----------------
extern "C" void kernel_launch(void* const* d_in, const int* in_sizes, int n_in,
                              void* d_out, int out_size, void* d_ws, size_t ws_size,
                              hipStream_t stream){
  // Per the harness contract, dtypes follow the reference: all float tensors fp32.
  const float* x     = (const float*)d_in[0];
  const int*   pos   = (const int*)  d_in[1];
  // d_in[2] = attn_mask (pure causal; reconstructed analytically)
  const float* Wqkv  = (const float*)d_in[3];
  const float* bqkv  = (const float*)d_in[4];
  const float* Wout  = (const float*)d_in[5];
  const float* bout  = (const float*)d_in[6];
  const float* sinks = (const float*)d_in[7];

  char* ws = (char*)d_ws;
  unsigned short* xb   = (unsigned short*)(ws);                      //  8,388,608 B
  unsigned short* wqb  = (unsigned short*)(ws + 8388608);            // 12,582,912 B
  unsigned short* wob  = (unsigned short*)(ws + 20971520);           //  8,388,608 B
  unsigned short* qkv  = (unsigned short*)(ws + 29360128);           // 12,582,912 B
  unsigned short* ctxb = (unsigned short*)(ws + 41943040);           //  8,388,608 B -> ~50.3 MB total

  cvt_bf16_kernel<<<dim3(4096), dim3(256), 0, stream>>>(x,    xb,  1048576);
  cvt_bf16_kernel<<<dim3(6144), dim3(256), 0, stream>>>(Wqkv, wqb, 1572864);
  cvt_bf16_kernel<<<dim3(4096), dim3(256), 0, stream>>>(Wout, wob, 1048576);

  // qkv = x @ Wqkv^T + bqkv   (M=2048, N=3072, K=2048), bf16 out
  gemm_bt<1><<<dim3(24, 16), dim3(256), 0, stream>>>(xb, wqb, bqkv, (void*)qkv, 2048, 3072, 2048);
  // YaRN rope on Q (32 heads) + K (8 heads), in place
  rope_kernel<<<dim3(2048, 40), dim3(64), 0, stream>>>(qkv, pos);
  // attention -> ctx (bf16, [s][h*64+d])
  attn_kernel<<<dim3(32, 32), dim3(256), 0, stream>>>(qkv, sinks, ctxb);
  // out = ctx @ Wout^T + bout  (M=2048, N=2048, K=2048), fp32 out to d_out
  gemm_bt<0><<<dim3(16, 16), dim3(256), 0, stream>>>(ctxb, wob, bout, d_out, 2048, 2048, 2048);
}

// Round 5
// 241.437 us; speedup vs baseline: 2.0635x; 2.0635x over previous
//
#include <hip/hip_runtime.h>
#include <cstdint>

#define S_LEN 2048
#define EMB   2048
#define NHEAD 32
#define NKV   8
#define HDIM  64
#define NQKV  3072   // (H+2G)*D

typedef __attribute__((ext_vector_type(8))) short bf16x8;
typedef __attribute__((ext_vector_type(4))) float f32x4;

__device__ __forceinline__ unsigned short f2bf(float f){
  union { float f; unsigned int u; } v; v.f = f;
  unsigned int r = v.u + 0x7FFFu + ((v.u >> 16) & 1u);
  return (unsigned short)(r >> 16);
}
__device__ __forceinline__ float bf2f(unsigned short u){
  union { unsigned int u; float f; } v; v.u = ((unsigned int)u) << 16;
  return v.f;
}

// ---------------- fp32 -> bf16 conversion (vectorized) ----------------
__global__ void cvt_bf16_kernel(const float* __restrict__ in,
                                unsigned short* __restrict__ out, int n4){
  int i = blockIdx.x * 256 + threadIdx.x;
  if (i < n4){
    const float4 v = ((const float4*)in)[i];
    ushort4 o;
    o.x = f2bf(v.x); o.y = f2bf(v.y); o.z = f2bf(v.z); o.w = f2bf(v.w);
    ((ushort4*)out)[i] = o;
  }
}

// ---------------- bf16 MFMA GEMM, C = A * B^T + bias (m97 structure) ----------------
template<int OUT_BF16>
__global__ __launch_bounds__(256) void gemm_bt(const unsigned short* __restrict__ A,
                                               const unsigned short* __restrict__ B,
                                               const float* __restrict__ bias,
                                               void* __restrict__ Cout,
                                               int M, int N, int K){
  __shared__ unsigned short As[128*32];
  __shared__ unsigned short Bs[128*32];
  const int tid  = threadIdx.x;
  const int lane = tid & 63;
  const int wid  = tid >> 6;
  const int m0 = blockIdx.y * 128;
  const int n0 = blockIdx.x * 128;
  const int wm = (wid >> 1) * 64;
  const int wn = (wid & 1) * 64;
  const int fm = lane & 15;
  const int q8 = (lane >> 4) * 8;

  f32x4 acc[4][4];
#pragma unroll
  for (int i = 0; i < 4; ++i)
#pragma unroll
    for (int j = 0; j < 4; ++j) acc[i][j] = {0.f, 0.f, 0.f, 0.f};

  const int srow = lane >> 2;
  const int scol = (lane & 3) * 8;
  const unsigned short* Ag = A + (size_t)(m0 + wid*32 + srow) * K + scol;
  const unsigned short* Bg = B + (size_t)(n0 + wid*32 + srow) * K + scol;
  unsigned short* AsW = &As[(wid*32)*32];
  unsigned short* BsW = &Bs[(wid*32)*32];

  for (int k0 = 0; k0 < K; k0 += 32){
    __syncthreads();
    __builtin_amdgcn_global_load_lds((const __attribute__((address_space(1))) void*)(Ag + k0),
        (__attribute__((address_space(3))) void*)AsW, 16, 0, 0);
    __builtin_amdgcn_global_load_lds((const __attribute__((address_space(1))) void*)(Ag + k0 + (size_t)16*K),
        (__attribute__((address_space(3))) void*)(AsW + 16*32), 16, 0, 0);
    __builtin_amdgcn_global_load_lds((const __attribute__((address_space(1))) void*)(Bg + k0),
        (__attribute__((address_space(3))) void*)BsW, 16, 0, 0);
    __builtin_amdgcn_global_load_lds((const __attribute__((address_space(1))) void*)(Bg + k0 + (size_t)16*K),
        (__attribute__((address_space(3))) void*)(BsW + 16*32), 16, 0, 0);
    __syncthreads();

    bf16x8 af[4], bfr[4];
#pragma unroll
    for (int i = 0; i < 4; ++i) af[i]  = *(const bf16x8*)&As[(wm + i*16 + fm)*32 + q8];
#pragma unroll
    for (int j = 0; j < 4; ++j) bfr[j] = *(const bf16x8*)&Bs[(wn + j*16 + fm)*32 + q8];
#pragma unroll
    for (int i = 0; i < 4; ++i)
#pragma unroll
      for (int j = 0; j < 4; ++j)
        acc[i][j] = __builtin_amdgcn_mfma_f32_16x16x32_bf16(af[i], bfr[j], acc[i][j], 0, 0, 0);
  }

  const int quad = lane >> 4;
#pragma unroll
  for (int j = 0; j < 4; ++j){
    const int col = n0 + wn + j*16 + fm;
    const float bv = bias[col];
#pragma unroll
    for (int i = 0; i < 4; ++i){
#pragma unroll
      for (int r = 0; r < 4; ++r){
        const int row = m0 + wm + i*16 + quad*4 + r;
        const float v = acc[i][j][r] + bv;
        if (OUT_BF16) ((unsigned short*)Cout)[(size_t)row*N + col] = f2bf(v);
        else          ((float*)Cout)[(size_t)row*N + col] = v;
      }
    }
  }
}

// ---------------- YaRN RoPE in-place on bf16 qkv ----------------
// grid 2048 (one block per position), 256 threads, 10 elems each (40 heads x 64 d).
// d/d^32 partners always land in the same 64-lane wave -> lockstep makes the
// in-place read-before-write safe without barriers.
__global__ __launch_bounds__(256) void rope_kernel(unsigned short* __restrict__ qkv,
                                                   const int* __restrict__ pos){
  const int s = blockIdx.x;
  const float ps = (float)pos[s];
  unsigned short* p = qkv + (size_t)s * NQKV;
  for (int e = threadIdx.x; e < 40*64; e += 256){
    const int head = e >> 6, d = e & 63;
    const int i = d & 31;
    const float freq = __expf(-(float)i * (9.210340371976184f / 32.0f));
    const float wl = 6.283185307179586f / freq;
    float t = (wl - 128.0f) * (1.0f / 3968.0f);
    t = fminf(fmaxf(t, 0.f), 1.f);
    const float eff = freq * (1.0f - 0.5f * t);
    const float ang = ps * eff * 1.0693147180559945f;
    const float c = cosf(ang), sn = sinf(ang);
    const int ch = (head < NHEAD) ? head*HDIM + d : EMB + (head - NHEAD)*HDIM + d;
    const float x  = bf2f(p[ch]);
    const float ot = (d < 32) ? bf2f(p[ch + 32]) : bf2f(p[ch - 32]);
    p[ch] = f2bf((d < 32) ? (x * c - ot * sn) : (x * c + ot * sn));
  }
}

// ---------------- MFMA flash attention: sliding-window GQA + sink ----------------
// grid (S/64, H), 256 threads (4 waves x 16 queries each). 64-key chunks.
__global__ __launch_bounds__(256) void attn_kernel(const unsigned short* __restrict__ qkv,
                                                   const float* __restrict__ sinks,
                                                   unsigned short* __restrict__ ctxb){
  const int h  = blockIdx.y;
  const int q0 = blockIdx.x * 64;
  const int g  = h >> 2;
  const int tid  = threadIdx.x;
  const int lane = tid & 63;
  const int wid  = tid >> 6;
  const int fm   = lane & 15;
  const int quad = lane >> 4;

  // K: split-K layout [ks][key][40], b128-aligned rows (80B)
  __shared__ unsigned short Ks[2*64*40];   // 10240 B
  // V^T: [kk][d][34] (kk = key>>5), stride 34 -> 4-way b16 writes, ~2-way b32 reads
  __shared__ unsigned short Vt[2*64*34];   //  8704 B
  // P per wave: [ks][q16][40]
  __shared__ unsigned short Pl[4*2*16*40]; // 10240 B   (total 29184 B)

  // Q A-frags direct from global (already roped): A[m=fm][k=quad*8+j+ks*32]
  const int qrow = q0 + wid*16 + fm;
  bf16x8 aq[2];
#pragma unroll
  for (int ks = 0; ks < 2; ++ks)
    aq[ks] = *(const bf16x8*)(qkv + (size_t)qrow*NQKV + h*HDIM + ks*32 + quad*8);

  f32x4 o[4];
#pragma unroll
  for (int nt = 0; nt < 4; ++nt) o[nt] = {0.f, 0.f, 0.f, 0.f};
  float m_[4], l_[4];
#pragma unroll
  for (int r = 0; r < 4; ++r){ m_[r] = -30000.f; l_[r] = 0.f; }

  const int qbase = q0 + wid*16 + quad*4;   // this lane's 4 query rows: qbase+r
  int cs0 = q0 - 128; if (cs0 < 0) cs0 = 0;

  unsigned short* plw = &Pl[wid*1280];

  for (int cs = cs0; cs <= q0; cs += 64){
    __syncthreads();
    // ---- stage K (natural split-K) and V (transposed) ----
#pragma unroll
    for (int it = 0; it < 2; ++it){
      const int e = (tid + it*256) * 8;
      const int key = e >> 6, d0 = e & 63;
      const unsigned short* kp = qkv + (size_t)(cs + key)*NQKV + EMB + g*HDIM + d0;
      *(bf16x8*)&Ks[(d0>>5)*2560 + key*40 + (d0 & 31)] = *(const bf16x8*)kp;
      const bf16x8 vv = *(const bf16x8*)(kp + NKV*HDIM);
      const unsigned short* vs = (const unsigned short*)&vv;
      unsigned short* vt = &Vt[(key>>5)*2176 + (key & 31)];
#pragma unroll
      for (int j = 0; j < 8; ++j) vt[(d0 + j)*34] = vs[j];
    }
    __syncthreads();

    // ---- QK^T: S[16q x 64k] per wave ----
    f32x4 sa[4];
#pragma unroll
    for (int nt = 0; nt < 4; ++nt){
      sa[nt] = {0.f, 0.f, 0.f, 0.f};
#pragma unroll
      for (int ks = 0; ks < 2; ++ks){
        const bf16x8 bk = *(const bf16x8*)&Ks[ks*2560 + (nt*16 + fm)*40 + quad*8];
        sa[nt] = __builtin_amdgcn_mfma_f32_16x16x32_bf16(aq[ks], bk, sa[nt], 0, 0, 0);
      }
    }

    // ---- scale + causal/sliding-window mask (C layout: col=key-in-tile, row=quad*4+r) ----
#pragma unroll
    for (int nt = 0; nt < 4; ++nt){
      const int key = cs + nt*16 + fm;
#pragma unroll
      for (int r = 0; r < 4; ++r){
        const float s = sa[nt][r] * 0.125f;
        const bool ok = (unsigned)(qbase + r - key) < 128u;  // 0 <= q-key <= 127
        sa[nt][r] = ok ? s : -1e30f;
      }
    }

    // ---- online softmax per query row (4 rows/lane, 4 shfl steps over 16-lane quad) ----
#pragma unroll
    for (int r = 0; r < 4; ++r){
      float t = fmaxf(fmaxf(sa[0][r], sa[1][r]), fmaxf(sa[2][r], sa[3][r]));
#pragma unroll
      for (int off = 1; off < 16; off <<= 1) t = fmaxf(t, __shfl_xor(t, off, 64));
      const float nm = fmaxf(m_[r], t);
      const float al = __expf(m_[r] - nm);
#pragma unroll
      for (int nt = 0; nt < 4; ++nt) sa[nt][r] = __expf(sa[nt][r] - nm);
      float ts = (sa[0][r] + sa[1][r]) + (sa[2][r] + sa[3][r]);
#pragma unroll
      for (int off = 1; off < 16; off <<= 1) ts += __shfl_xor(ts, off, 64);
      l_[r] = l_[r]*al + ts;
      m_[r] = nm;
#pragma unroll
      for (int nt = 0; nt < 4; ++nt) o[nt][r] *= al;
    }

    // ---- P (C layout) -> LDS bf16 [ks][q][40] ----
#pragma unroll
    for (int nt = 0; nt < 4; ++nt)
#pragma unroll
      for (int r = 0; r < 4; ++r)
        plw[(nt>>1)*640 + (quad*4 + r)*40 + (nt&1)*16 + fm] = f2bf(sa[nt][r]);
    __asm__ volatile("s_waitcnt lgkmcnt(0)" ::: "memory");

    // ---- PV: A = P [m=q][k=key] frags, B = Vt [n=d][k=key] frags ----
    bf16x8 pa[2];
#pragma unroll
    for (int ks = 0; ks < 2; ++ks)
      pa[ks] = *(const bf16x8*)&plw[ks*640 + fm*40 + quad*8];
    const unsigned int* vb = (const unsigned int*)Vt;
#pragma unroll
    for (int nt = 0; nt < 4; ++nt){
#pragma unroll
      for (int ks = 0; ks < 2; ++ks){
        const int ui = ks*1088 + (nt*16 + fm)*17 + quad*4;
        union { unsigned int u[4]; bf16x8 v; } bb;
        bb.u[0] = vb[ui+0]; bb.u[1] = vb[ui+1]; bb.u[2] = vb[ui+2]; bb.u[3] = vb[ui+3];
        o[nt] = __builtin_amdgcn_mfma_f32_16x16x32_bf16(pa[ks], bb.v, o[nt], 0, 0, 0);
      }
    }
  }

  // ---- finalize with sink, write ctx (bf16) ----
  const float snk = sinks[h];
#pragma unroll
  for (int r = 0; r < 4; ++r){
    const float nm = fmaxf(m_[r], snk);
    const float e  = __expf(m_[r] - nm);
    const float denom = l_[r]*e + __expf(snk - nm);
    const float sc = e / denom;
    const size_t row = (size_t)(qbase + r)*EMB + h*HDIM;
#pragma unroll
    for (int nt = 0; nt < 4; ++nt)
      ctxb[row + nt*16 + fm] = f2bf(o[nt][r] * sc);
  }
}

// ---------------- launch ----------------
extern "C" void kernel_launch(void* const* d_in, const int* in_sizes, int n_in,
                              void* d_out, int out_size, void* d_ws, size_t ws_size,
                              hipStream_t stream){
  const float* x     = (const float*)d_in[0];
  const int*   pos   = (const int*)  d_in[1];
  const float* Wqkv  = (const float*)d_in[3];
  const float* bqkv  = (const float*)d_in[4];
  const float* Wout  = (const float*)d_in[5];
  const float* bout  = (const float*)d_in[6];
  const float* sinks = (const float*)d_in[7];

  char* ws = (char*)d_ws;
  unsigned short* xb   = (unsigned short*)(ws);                      //  8,388,608 B
  unsigned short* wqb  = (unsigned short*)(ws + 8388608);            // 12,582,912 B
  unsigned short* wob  = (unsigned short*)(ws + 20971520);           //  8,388,608 B
  unsigned short* qkv  = (unsigned short*)(ws + 29360128);           // 12,582,912 B
  unsigned short* ctxb = (unsigned short*)(ws + 41943040);           //  8,388,608 B

  cvt_bf16_kernel<<<dim3(4096), dim3(256), 0, stream>>>(x,    xb,  1048576);
  cvt_bf16_kernel<<<dim3(6144), dim3(256), 0, stream>>>(Wqkv, wqb, 1572864);
  cvt_bf16_kernel<<<dim3(4096), dim3(256), 0, stream>>>(Wout, wob, 1048576);

  gemm_bt<1><<<dim3(24, 16), dim3(256), 0, stream>>>(xb, wqb, bqkv, (void*)qkv, 2048, 3072, 2048);
  rope_kernel<<<dim3(2048), dim3(256), 0, stream>>>(qkv, pos);
  attn_kernel<<<dim3(32, 32), dim3(256), 0, stream>>>(qkv, sinks, ctxb);
  gemm_bt<0><<<dim3(16, 16), dim3(256), 0, stream>>>(ctxb, wob, bout, d_out, 2048, 2048, 2048);
}

// Round 6
// 214.539 us; speedup vs baseline: 2.3223x; 1.1254x over previous
//
#include <hip/hip_runtime.h>
#include <cstdint>

#define S_LEN 2048
#define EMB   2048
#define NHEAD 32
#define NKV   8
#define HDIM  64
#define NQKV  3072   // (H+2G)*D

typedef __attribute__((ext_vector_type(8))) short bf16x8;
typedef __attribute__((ext_vector_type(4))) float f32x4;

__device__ __forceinline__ unsigned short f2bf(float f){
  union { float f; unsigned int u; } v; v.f = f;
  unsigned int r = v.u + 0x7FFFu + ((v.u >> 16) & 1u);
  return (unsigned short)(r >> 16);
}
__device__ __forceinline__ float bf2f(unsigned short u){
  union { unsigned int u; float f; } v; v.u = ((unsigned int)u) << 16;
  return v.f;
}

// ---------------- fp32 -> bf16 conversion, 3 tensors in one launch ----------------
__global__ __launch_bounds__(256) void cvt3_kernel(const float* __restrict__ a, unsigned short* __restrict__ da, int na,
                                                   const float* __restrict__ b, unsigned short* __restrict__ db, int nb,
                                                   const float* __restrict__ c, unsigned short* __restrict__ dc, int nc){
  int i = blockIdx.x * 256 + threadIdx.x;
  const float* s; unsigned short* d;
  if (i < na){ s = a; d = da; }
  else if (i < na + nb){ s = b; d = db; i -= na; }
  else if (i < na + nb + nc){ s = c; d = dc; i -= na + nb; }
  else return;
  const float4 v = ((const float4*)s)[i];
  ushort4 o;
  o.x = f2bf(v.x); o.y = f2bf(v.y); o.z = f2bf(v.z); o.w = f2bf(v.w);
  ((ushort4*)d)[i] = o;
}

// ---------------- bf16 MFMA GEMM, C = A * B^T + bias, 64x128 tile ----------------
// A: M x K row-major bf16; B: N x K row-major bf16; bias fp32[N].
// ROPE=1: apply YaRN rope to channels < 2560 in the epilogue (gemm1 only).
template<int OUT_BF16, int ROPE>
__global__ __launch_bounds__(256) void gemm_bt(const unsigned short* __restrict__ A,
                                               const unsigned short* __restrict__ B,
                                               const float* __restrict__ bias,
                                               void* __restrict__ Cout,
                                               const int* __restrict__ pos,
                                               int M, int N, int K){
  __shared__ unsigned short As[64*32];    // 4 KB
  __shared__ unsigned short Bs[128*32];   // 8 KB
  const int tid  = threadIdx.x;
  const int lane = tid & 63;
  const int wid  = tid >> 6;
  const int m0 = blockIdx.y * 64;
  const int n0 = blockIdx.x * 128;
  const int wm = (wid >> 1) * 32;
  const int wn = (wid & 1) * 64;
  const int fm = lane & 15;
  const int q8 = (lane >> 4) * 8;
  const int quad = lane >> 4;

  f32x4 acc[2][4];
#pragma unroll
  for (int i = 0; i < 2; ++i)
#pragma unroll
    for (int j = 0; j < 4; ++j) acc[i][j] = {0.f, 0.f, 0.f, 0.f};

  // staging: wave stages 16 A-rows (1 issue) + 32 B-rows (2 issues); 16B/lane.
  const int srow = lane >> 2;
  const int scol = (lane & 3) * 8;
  const unsigned short* Ag = A + (size_t)(m0 + wid*16 + srow) * K + scol;
  const unsigned short* Bg = B + (size_t)(n0 + wid*32 + srow) * K + scol;
  unsigned short* AsW = &As[(wid*16)*32];
  unsigned short* BsW = &Bs[(wid*32)*32];

  for (int k0 = 0; k0 < K; k0 += 32){
    __syncthreads();
    __builtin_amdgcn_global_load_lds((const __attribute__((address_space(1))) void*)(Ag + k0),
        (__attribute__((address_space(3))) void*)AsW, 16, 0, 0);
    __builtin_amdgcn_global_load_lds((const __attribute__((address_space(1))) void*)(Bg + k0),
        (__attribute__((address_space(3))) void*)BsW, 16, 0, 0);
    __builtin_amdgcn_global_load_lds((const __attribute__((address_space(1))) void*)(Bg + k0 + (size_t)16*K),
        (__attribute__((address_space(3))) void*)(BsW + 16*32), 16, 0, 0);
    __syncthreads();

    bf16x8 af[2], bfr[4];
#pragma unroll
    for (int i = 0; i < 2; ++i) af[i]  = *(const bf16x8*)&As[(wm + i*16 + fm)*32 + q8];
#pragma unroll
    for (int j = 0; j < 4; ++j) bfr[j] = *(const bf16x8*)&Bs[(wn + j*16 + fm)*32 + q8];
#pragma unroll
    for (int i = 0; i < 2; ++i)
#pragma unroll
      for (int j = 0; j < 4; ++j)
        acc[i][j] = __builtin_amdgcn_mfma_f32_16x16x32_bf16(af[i], bfr[j], acc[i][j], 0, 0, 0);
  }

  // ---- epilogue: bias, optional fused YaRN rope, store ----
  // C/D layout: col = lane&15 (+j*16), row = quad*4 + reg (+i*16)  [m89/m91]
  float v[2][4][4];
#pragma unroll
  for (int j = 0; j < 4; ++j){
    const float bv = bias[n0 + wn + j*16 + fm];
#pragma unroll
    for (int i = 0; i < 2; ++i)
#pragma unroll
      for (int r = 0; r < 4; ++r) v[i][j][r] = acc[i][j][r] + bv;
  }

  if (ROPE && (n0 + wn) < 2560){   // Q channels 0..2047, K 2048..2559; V untouched
    // d = j*16+fm in [0,64); freq index = d&31 = (j&1)*16+fm; half = (j>=2).
    // Partner channel d^32 lives in this lane's acc[i][j^2][r].
    float cc[2][4][2], ss[2][4][2];
#pragma unroll
    for (int jp = 0; jp < 2; ++jp){
      const float ifr = (float)(jp*16 + fm);
      const float freq = __expf(-ifr * (9.210340371976184f / 32.0f));  // 10000^(-2i/64)
      const float wl = 6.283185307179586f / freq;
      float t = fminf(fmaxf((wl - 128.0f) * (1.0f / 3968.0f), 0.f), 1.f);
      const float eff = freq * (1.0f - 0.5f * t) * 1.0693147180559945f; // *conc
#pragma unroll
      for (int i = 0; i < 2; ++i)
#pragma unroll
        for (int r = 0; r < 4; ++r){
          const int row = m0 + wm + i*16 + quad*4 + r;
          const float ang = (float)pos[row] * eff;
          __sincosf(ang, &ss[i][r][jp], &cc[i][r][jp]);
        }
    }
    float o[2][4][4];
#pragma unroll
    for (int i = 0; i < 2; ++i)
#pragma unroll
      for (int j = 0; j < 4; ++j){
        const int jp = j & 1;
        const float sgn = (j < 2) ? -1.f : 1.f;
#pragma unroll
        for (int r = 0; r < 4; ++r)
          o[i][j][r] = v[i][j][r]*cc[i][r][jp] + sgn*v[i][j^2][r]*ss[i][r][jp];
      }
#pragma unroll
    for (int i = 0; i < 2; ++i)
#pragma unroll
      for (int j = 0; j < 4; ++j)
#pragma unroll
        for (int r = 0; r < 4; ++r) v[i][j][r] = o[i][j][r];
  }

#pragma unroll
  for (int j = 0; j < 4; ++j){
    const int col = n0 + wn + j*16 + fm;
#pragma unroll
    for (int i = 0; i < 2; ++i){
#pragma unroll
      for (int r = 0; r < 4; ++r){
        const int row = m0 + wm + i*16 + quad*4 + r;
        if (OUT_BF16) ((unsigned short*)Cout)[(size_t)row*N + col] = f2bf(v[i][j][r]);
        else          ((float*)Cout)[(size_t)row*N + col] = v[i][j][r];
      }
    }
  }
}

// ---------------- MFMA flash attention: sliding-window GQA + sink ----------------
// grid (S/64, H), 256 threads (4 waves x 16 queries each). 64-key chunks.
__global__ __launch_bounds__(256) void attn_kernel(const unsigned short* __restrict__ qkv,
                                                   const float* __restrict__ sinks,
                                                   unsigned short* __restrict__ ctxb){
  const int h  = blockIdx.y;
  const int q0 = blockIdx.x * 64;
  const int g  = h >> 2;
  const int tid  = threadIdx.x;
  const int lane = tid & 63;
  const int wid  = tid >> 6;
  const int fm   = lane & 15;
  const int quad = lane >> 4;

  __shared__ unsigned short Ks[2*64*40];   // split-K [ks][key][40]
  __shared__ unsigned short Vt[2*64*34];   // V^T [kk][d][34]
  __shared__ unsigned short Pl[4*2*16*40]; // per-wave P [ks][q16][40]

  const int qrow = q0 + wid*16 + fm;
  bf16x8 aq[2];
#pragma unroll
  for (int ks = 0; ks < 2; ++ks)
    aq[ks] = *(const bf16x8*)(qkv + (size_t)qrow*NQKV + h*HDIM + ks*32 + quad*8);

  f32x4 o[4];
#pragma unroll
  for (int nt = 0; nt < 4; ++nt) o[nt] = {0.f, 0.f, 0.f, 0.f};
  float m_[4], l_[4];
#pragma unroll
  for (int r = 0; r < 4; ++r){ m_[r] = -30000.f; l_[r] = 0.f; }

  const int qbase = q0 + wid*16 + quad*4;
  int cs0 = q0 - 128; if (cs0 < 0) cs0 = 0;
  unsigned short* plw = &Pl[wid*1280];

  for (int cs = cs0; cs <= q0; cs += 64){
    __syncthreads();
#pragma unroll
    for (int it = 0; it < 2; ++it){
      const int e = (tid + it*256) * 8;
      const int key = e >> 6, d0 = e & 63;
      const unsigned short* kp = qkv + (size_t)(cs + key)*NQKV + EMB + g*HDIM + d0;
      *(bf16x8*)&Ks[(d0>>5)*2560 + key*40 + (d0 & 31)] = *(const bf16x8*)kp;
      const bf16x8 vv = *(const bf16x8*)(kp + NKV*HDIM);
      const unsigned short* vs = (const unsigned short*)&vv;
      unsigned short* vt = &Vt[(key>>5)*2176 + (key & 31)];
#pragma unroll
      for (int j = 0; j < 8; ++j) vt[(d0 + j)*34] = vs[j];
    }
    __syncthreads();

    f32x4 sa[4];
#pragma unroll
    for (int nt = 0; nt < 4; ++nt){
      sa[nt] = {0.f, 0.f, 0.f, 0.f};
#pragma unroll
      for (int ks = 0; ks < 2; ++ks){
        const bf16x8 bk = *(const bf16x8*)&Ks[ks*2560 + (nt*16 + fm)*40 + quad*8];
        sa[nt] = __builtin_amdgcn_mfma_f32_16x16x32_bf16(aq[ks], bk, sa[nt], 0, 0, 0);
      }
    }

#pragma unroll
    for (int nt = 0; nt < 4; ++nt){
      const int key = cs + nt*16 + fm;
#pragma unroll
      for (int r = 0; r < 4; ++r){
        const float s = sa[nt][r] * 0.125f;
        const bool ok = (unsigned)(qbase + r - key) < 128u;
        sa[nt][r] = ok ? s : -1e30f;
      }
    }

#pragma unroll
    for (int r = 0; r < 4; ++r){
      float t = fmaxf(fmaxf(sa[0][r], sa[1][r]), fmaxf(sa[2][r], sa[3][r]));
#pragma unroll
      for (int off = 1; off < 16; off <<= 1) t = fmaxf(t, __shfl_xor(t, off, 64));
      const float nm = fmaxf(m_[r], t);
      const float al = __expf(m_[r] - nm);
#pragma unroll
      for (int nt = 0; nt < 4; ++nt) sa[nt][r] = __expf(sa[nt][r] - nm);
      float ts = (sa[0][r] + sa[1][r]) + (sa[2][r] + sa[3][r]);
#pragma unroll
      for (int off = 1; off < 16; off <<= 1) ts += __shfl_xor(ts, off, 64);
      l_[r] = l_[r]*al + ts;
      m_[r] = nm;
#pragma unroll
      for (int nt = 0; nt < 4; ++nt) o[nt][r] *= al;
    }

#pragma unroll
    for (int nt = 0; nt < 4; ++nt)
#pragma unroll
      for (int r = 0; r < 4; ++r)
        plw[(nt>>1)*640 + (quad*4 + r)*40 + (nt&1)*16 + fm] = f2bf(sa[nt][r]);
    __asm__ volatile("s_waitcnt lgkmcnt(0)" ::: "memory");

    bf16x8 pa[2];
#pragma unroll
    for (int ks = 0; ks < 2; ++ks)
      pa[ks] = *(const bf16x8*)&plw[ks*640 + fm*40 + quad*8];
    const unsigned int* vb = (const unsigned int*)Vt;
#pragma unroll
    for (int nt = 0; nt < 4; ++nt){
#pragma unroll
      for (int ks = 0; ks < 2; ++ks){
        const int ui = ks*1088 + (nt*16 + fm)*17 + quad*4;
        union { unsigned int u[4]; bf16x8 v; } bb;
        bb.u[0] = vb[ui+0]; bb.u[1] = vb[ui+1]; bb.u[2] = vb[ui+2]; bb.u[3] = vb[ui+3];
        o[nt] = __builtin_amdgcn_mfma_f32_16x16x32_bf16(pa[ks], bb.v, o[nt], 0, 0, 0);
      }
    }
  }

  const float snk = sinks[h];
#pragma unroll
  for (int r = 0; r < 4; ++r){
    const float nm = fmaxf(m_[r], snk);
    const float e  = __expf(m_[r] - nm);
    const float denom = l_[r]*e + __expf(snk - nm);
    const float sc = e / denom;
    const size_t row = (size_t)(qbase + r)*EMB + h*HDIM;
#pragma unroll
    for (int nt = 0; nt < 4; ++nt)
      ctxb[row + nt*16 + fm] = f2bf(o[nt][r] * sc);
  }
}

// ---------------- launch ----------------
extern "C" void kernel_launch(void* const* d_in, const int* in_sizes, int n_in,
                              void* d_out, int out_size, void* d_ws, size_t ws_size,
                              hipStream_t stream){
  const float* x     = (const float*)d_in[0];
  const int*   pos   = (const int*)  d_in[1];
  const float* Wqkv  = (const float*)d_in[3];
  const float* bqkv  = (const float*)d_in[4];
  const float* Wout  = (const float*)d_in[5];
  const float* bout  = (const float*)d_in[6];
  const float* sinks = (const float*)d_in[7];

  char* ws = (char*)d_ws;
  unsigned short* xb   = (unsigned short*)(ws);                      //  8,388,608 B
  unsigned short* wqb  = (unsigned short*)(ws + 8388608);            // 12,582,912 B
  unsigned short* wob  = (unsigned short*)(ws + 20971520);           //  8,388,608 B
  unsigned short* qkv  = (unsigned short*)(ws + 29360128);           // 12,582,912 B
  unsigned short* ctxb = (unsigned short*)(ws + 41943040);           //  8,388,608 B

  cvt3_kernel<<<dim3(14336), dim3(256), 0, stream>>>(x, xb, 1048576,
                                                     Wqkv, wqb, 1572864,
                                                     Wout, wob, 1048576);

  // qkv = rope(x @ Wqkv^T + bqkv)   (M=2048, N=3072, K=2048), bf16 out
  gemm_bt<1,1><<<dim3(24, 32), dim3(256), 0, stream>>>(xb, wqb, bqkv, (void*)qkv, pos, 2048, 3072, 2048);
  // attention -> ctx (bf16, [s][h*64+d])
  attn_kernel<<<dim3(32, 32), dim3(256), 0, stream>>>(qkv, sinks, ctxb);
  // out = ctx @ Wout^T + bout  (M=2048, N=2048, K=2048), fp32 out to d_out
  gemm_bt<0,0><<<dim3(16, 32), dim3(256), 0, stream>>>(ctxb, wob, bout, d_out, nullptr, 2048, 2048, 2048);
}